// Round 17
// baseline (125.839 us; speedup 1.0000x reference)
//
#include <hip/hip_runtime.h>
#include <math.h>

#define CC    144
#define WW    9225
#define KWW   10
#define FF    64
#define H1N   128
#define CONVN (WW - KWW + 1)    // 9216
#define CFN   (CC * FF)         // 9216
#define CATN  (CFN + CONVN)     // 18432
#define CONVB 36                // conv blocks (first in grid)
#define SWEEPB 2048             // sweep blocks
#define GRIDTH (SWEEPB * 256)   // 524288 sweep threads
#define NQ8   (CC * FF * WW / 8)      // 10,627,200 8-float units
#define ADVF  (GRIDTH * 8)            // 4,194,304 floats advanced per iter
#define DR    (ADVF / WW)             // 454
#define RREM  (ADVF % WW)             // 6154
#define L1B   256

typedef float f32x4  __attribute__((ext_vector_type(4)));
typedef float f32x4u __attribute__((ext_vector_type(4), aligned(4)));

// ---------------------------------------------------------------------------
// k_init: concat[r] = bfc[r] for the fc region (sweep atomics accumulate on top)
// ---------------------------------------------------------------------------
__global__ __launch_bounds__(256) void k_init(
    const float* __restrict__ bfc, float* __restrict__ concat)
{
    const int i = blockIdx.x * 256 + threadIdx.x;
    if (i < CFN) concat[i] = bfc[i];
}

// ---------------------------------------------------------------------------
// k_sweep: ONE chip-wide moving frontier over flat Wfc (fill/copy-like access,
// the only patterns measured >6.3 TB/s). Each thread takes 8 consecutive
// floats per step; wave window = 2KB consecutive; row index maintained
// incrementally (no div in loop). Segmented wave reduce (<=1 row boundary per
// window), one atomicAdd per wave per window into concat[row].
//   bids [0,CONVB): conv (256 positions each). bids [CONVB, +SWEEPB): sweep.
// ---------------------------------------------------------------------------
__global__ __launch_bounds__(256) void k_sweep(
    const float* __restrict__ x,     // [C, W]
    const float* __restrict__ Wfc,   // [C, F, W] flat
    const float* __restrict__ Kc,    // [C, KW]
    const float* __restrict__ bconv, // [1]
    float* __restrict__ concat)      // [CATN]
{
    __shared__ float kc[CC * KWW];
    const int bid = blockIdx.x;
    const int tid = threadIdx.x;

    if (bid < CONVB) {
        // ---------------- conv: position p = bid*256 + tid ----------------
        for (int i = tid; i < CC * KWW; i += 256) kc[i] = Kc[i];
        __syncthreads();
        const int p = bid * 256 + tid;
        float acc = bconv[0];
        for (int c2 = 0; c2 < CC; ++c2) {
            const float* __restrict__ xr = x + (size_t)c2 * WW + p;
            const float* __restrict__ kr = kc + c2 * KWW;
            #pragma unroll
            for (int k = 0; k < KWW; ++k)
                acc = fmaf(xr[k], kr[k], acc);
        }
        concat[CFN + p] = acc;
        return;
    }

    // ---------------- fc sweep ----------------
    const int gid  = (bid - CONVB) * 256 + tid;
    const int lane = tid & 63;
    unsigned flat = (unsigned)gid * 8u;
    int r   = (int)(flat / WW);          // one-time division
    int off = (int)(flat % WW);

    for (unsigned j = (unsigned)gid; j < (unsigned)NQ8; j += (unsigned)GRIDTH) {
        const float* __restrict__ wp = Wfc + (size_t)j * 8u;   // 32B-aligned
        const f32x4 w0 = __builtin_nontemporal_load((const f32x4*)wp);
        const f32x4 w1 = __builtin_nontemporal_load((const f32x4*)wp + 1);

        float pa = 0.f, pb = 0.f;
        const int c = r >> 6;
        if (off <= WW - 8) {
            const f32x4u* __restrict__ xp =
                (const f32x4u*)(x + (size_t)c * WW + off);
            const f32x4 x0 = xp[0], x1 = xp[1];
            pa = w0.x * x0.x + w0.y * x0.y + w0.z * x0.z + w0.w * x0.w
               + w1.x * x1.x + w1.y * x1.y + w1.z * x1.z + w1.w * x1.w;
        } else {
            // rare: window's 8 floats straddle a row boundary
            const float wv[8] = {w0.x, w0.y, w0.z, w0.w, w1.x, w1.y, w1.z, w1.w};
            const int c2 = (r + 1) >> 6;
            #pragma unroll
            for (int k = 0; k < 8; ++k) {
                const int e = off + k;
                if (e < WW) pa = fmaf(wv[k], x[(size_t)c  * WW + e],        pa);
                else        pb = fmaf(wv[k], x[(size_t)c2 * WW + (e - WW)], pb);
            }
        }

        // segmented wave reduce: rows present are r0 and (maybe) r0+1
        const int r0 = __builtin_amdgcn_readfirstlane(r);
        float ga = (r == r0) ? pa : 0.f;   // contributions to row r0
        float gb = (r == r0) ? pb : pa;    // contributions to row r0+1
        const int cross = __any(gb != 0.f);
        #pragma unroll
        for (int o = 32; o; o >>= 1) ga += __shfl_xor(ga, o, 64);
        if (cross) {
            #pragma unroll
            for (int o = 32; o; o >>= 1) gb += __shfl_xor(gb, o, 64);
        }
        if (lane == 0) {
            atomicAdd(&concat[r0], ga);
            if (cross) atomicAdd(&concat[r0 + 1], gb);
        }

        // advance frontier (compile-time constants; no division)
        off += RREM; r += DR;
        if (off >= WW) { off -= WW; ++r; }
    }
}

// ---------------------------------------------------------------------------
// Stage 2: 256 blocks; block j = (h = j>>1, half = j&1) half-row partial dot.
// ---------------------------------------------------------------------------
__global__ __launch_bounds__(256) void k_layer1_v2(
    const float* __restrict__ W1,     // [H1, CAT]
    const float* __restrict__ concat, // [CAT]
    float* __restrict__ partial)      // [256]
{
    __shared__ float sm[4];
    const int j = blockIdx.x, tid = threadIdx.x;
    const int h = j >> 1, half = j & 1;
    const f32x4* __restrict__ wr =
        (const f32x4*)(W1 + (size_t)h * CATN + half * (CATN / 2));
    const f32x4* __restrict__ cv =
        (const f32x4*)(concat + half * (CATN / 2));

    float acc = 0.f;
    for (int i = tid; i < CATN / 8; i += 256) {   // 9 iters
        const f32x4 a = wr[i];
        const f32x4 q = cv[i];
        acc += a.x * q.x + a.y * q.y + a.z * q.z + a.w * q.w;
    }
    #pragma unroll
    for (int off = 32; off > 0; off >>= 1)
        acc += __shfl_xor(acc, off, 64);
    if ((tid & 63) == 0) sm[tid >> 6] = acc;
    __syncthreads();
    if (tid == 0)
        partial[j] = sm[0] + sm[1] + sm[2] + sm[3];
}

// ---------------------------------------------------------------------------
// Stage 3: combine partials + bias + relu, dot with W2, relu, sigmoid.
// ---------------------------------------------------------------------------
__global__ __launch_bounds__(128) void k_final_v2(
    const float* __restrict__ partial, // [256]
    const float* __restrict__ b1,      // [H1]
    const float* __restrict__ W2,      // [1, H1]
    const float* __restrict__ b2,      // [1]
    float* __restrict__ out)           // [1]
{
    __shared__ float sm[2];
    const int tid = threadIdx.x;
    float v = fmaxf(partial[2 * tid] + partial[2 * tid + 1] + b1[tid], 0.f)
              * W2[tid];
    #pragma unroll
    for (int off = 32; off > 0; off >>= 1)
        v += __shfl_xor(v, off, 64);
    if ((tid & 63) == 0) sm[tid >> 6] = v;
    __syncthreads();
    if (tid == 0) {
        float z = sm[0] + sm[1] + b2[0];
        z = fmaxf(z, 0.f);
        out[0] = 1.f / (1.f + expf(-z));
    }
}

extern "C" void kernel_launch(void* const* d_in, const int* in_sizes, int n_in,
                              void* d_out, int out_size, void* d_ws, size_t ws_size,
                              hipStream_t stream) {
    const float* x     = (const float*)d_in[0];
    const float* Wfc   = (const float*)d_in[1];
    const float* bfc   = (const float*)d_in[2];
    const float* Kc    = (const float*)d_in[3];
    const float* bconv = (const float*)d_in[4];
    const float* W1    = (const float*)d_in[5];
    const float* b1    = (const float*)d_in[6];
    const float* W2    = (const float*)d_in[7];
    const float* b2    = (const float*)d_in[8];
    float* out = (float*)d_out;

    float* concat  = (float*)d_ws;         // [CATN]
    float* partial = concat + CATN;        // [256]

    k_init     <<<(CFN + 255) / 256, 256, 0, stream>>>(bfc, concat);
    k_sweep    <<<CONVB + SWEEPB,    256, 0, stream>>>(x, Wfc, Kc, bconv, concat);
    k_layer1_v2<<<L1B,               256, 0, stream>>>(W1, concat, partial);
    k_final_v2 <<<1,                 128, 0, stream>>>(partial, b1, W2, b2, out);
}

// Round 18
// 76.581 us; speedup vs baseline: 1.6432x; 1.6432x over previous
//
#include <hip/hip_runtime.h>
#include <math.h>

#define CC    144
#define WW    9225
#define KWW   10
#define FF    64
#define H1N   128
#define CONVN (WW - KWW + 1)   // 9216
#define CFN   (CC * FF)        // 9216
#define CATN  (CFN + CONVN)    // 18432
#define FCB2  (CC * 8)         // 1152 fc blocks: (channel c, f-group g of 8)
#define NV4   36               // 36 iters * 64 lanes * 4 floats = 9216
#define NTAIL 9                // 9225 - 9216
#define HOTC  96               // c < HOTC: normal loads; c >= HOTC: nontemporal

typedef float f32x4  __attribute__((ext_vector_type(4)));
typedef float f32x4u __attribute__((ext_vector_type(4), aligned(4)));

// ---------------------------------------------------------------------------
// Stage 1 v9 (best measured: 76.5us total): x row staged in LDS; each wave
// streams two contiguous Wfc rows as lane-consecutive float4; HOTC nt split
// (the two proven wins: nt-split -8.6us, float4 W -3.7us). Read stream runs
// at ~5.1 TB/s — the empirical ceiling after 7 falsified structural theories.
//   blocks [0, FCB2): fc.  blocks [FCB2, FCB2+36): conv (256 positions each).
// ---------------------------------------------------------------------------
__global__ __launch_bounds__(256) void k_front_v9(
    const float* __restrict__ x,     // [C, W]
    const float* __restrict__ Wfc,   // [C, F, W]
    const float* __restrict__ bfc,   // [C, F]
    const float* __restrict__ Kc,    // [C, KW]
    const float* __restrict__ bconv, // [1]
    float* __restrict__ concat)      // [CATN]
{
    __shared__ float smem[WW];       // 36.9 KB; conv blocks use first 1440
    const int bid = blockIdx.x;
    const int tid = threadIdx.x;

    if (bid < FCB2) {
        const int c = bid >> 3;                   // channel
        const int g = bid & 7;                    // f-group
        const float* __restrict__ xr = x + (size_t)c * WW;

        // ---- stage x row into LDS (coalesced)
        for (int i = tid; i < WW; i += 256) smem[i] = xr[i];
        __syncthreads();

        // ---- each wave: rows r0, r0+1 as float4 streams
        const int wave = tid >> 6;
        const int lane = tid & 63;
        const int f0   = g * 8 + wave * 2;
        const int r0   = (c << 6) + f0;           // fc row index
        const f32x4u* __restrict__ w0v =
            (const f32x4u*)(Wfc + (size_t)r0 * WW);
        const f32x4u* __restrict__ w1v =
            (const f32x4u*)(Wfc + (size_t)(r0 + 1) * WW);
        const f32x4* __restrict__ xv = (const f32x4*)smem;  // 16B-aligned

        float a0 = 0.f, a1 = 0.f;
        if (c < HOTC) {
            #pragma unroll 6
            for (int i = 0; i < NV4; ++i) {
                const int q = i * 64 + lane;      // float4 index
                const f32x4 xq = xv[q];
                const f32x4 wq0 = w0v[q];
                const f32x4 wq1 = w1v[q];
                a0 += wq0.x * xq.x + wq0.y * xq.y + wq0.z * xq.z + wq0.w * xq.w;
                a1 += wq1.x * xq.x + wq1.y * xq.y + wq1.z * xq.z + wq1.w * xq.w;
            }
        } else {
            #pragma unroll 6
            for (int i = 0; i < NV4; ++i) {
                const int q = i * 64 + lane;
                const f32x4 xq = xv[q];
                const f32x4 wq0 = __builtin_nontemporal_load(w0v + q);
                const f32x4 wq1 = __builtin_nontemporal_load(w1v + q);
                a0 += wq0.x * xq.x + wq0.y * xq.y + wq0.z * xq.z + wq0.w * xq.w;
                a1 += wq1.x * xq.x + wq1.y * xq.y + wq1.z * xq.z + wq1.w * xq.w;
            }
        }
        // tail: elements 9216..9224
        if (lane < NTAIL) {
            const int e = NV4 * 256 + lane;       // 9216 + lane
            const float xq = smem[e];
            const float* __restrict__ wb = Wfc + (size_t)r0 * WW;
            a0 = fmaf(wb[e],      xq, a0);
            a1 = fmaf(wb[WW + e], xq, a1);
        }

        // wave-only reduction — no LDS, no __syncthreads
        #pragma unroll
        for (int off = 32; off > 0; off >>= 1) {
            a0 += __shfl_xor(a0, off, 64);
            a1 += __shfl_xor(a1, off, 64);
        }
        if (lane == 0) {
            concat[r0]     = a0 + bfc[r0];
            concat[r0 + 1] = a1 + bfc[r0 + 1];
        }
    } else {
        // ---- conv: position p = (bid-FCB2)*256 + tid
        for (int i = tid; i < CC * KWW; i += 256) smem[i] = Kc[i];
        __syncthreads();

        const int p = (bid - FCB2) * 256 + tid;   // 36*256 == 9216 exactly
        float acc = bconv[0];
        for (int c = 0; c < CC; ++c) {
            const float* __restrict__ xr = x + (size_t)c * WW + p;
            const float* __restrict__ kr = smem + c * KWW;
            #pragma unroll
            for (int k = 0; k < KWW; ++k)
                acc = fmaf(xr[k], kr[k], acc);
        }
        concat[CFN + p] = acc;
    }
}

// ---------------------------------------------------------------------------
// Stage 2: 256 blocks; block j = (h = j>>1, half = j&1) half-row partial dot.
// ---------------------------------------------------------------------------
__global__ __launch_bounds__(256) void k_layer1_v2(
    const float* __restrict__ W1,     // [H1, CAT]
    const float* __restrict__ concat, // [CAT]
    float* __restrict__ partial)      // [256]
{
    __shared__ float sm[4];
    const int j = blockIdx.x, tid = threadIdx.x;
    const int h = j >> 1, half = j & 1;
    const f32x4* __restrict__ wr =
        (const f32x4*)(W1 + (size_t)h * CATN + half * (CATN / 2));
    const f32x4* __restrict__ cv =
        (const f32x4*)(concat + half * (CATN / 2));

    float acc = 0.f;
    for (int i = tid; i < CATN / 8; i += 256) {   // 9 iters
        const f32x4 a = wr[i];
        const f32x4 q = cv[i];
        acc += a.x * q.x + a.y * q.y + a.z * q.z + a.w * q.w;
    }
    #pragma unroll
    for (int off = 32; off > 0; off >>= 1)
        acc += __shfl_xor(acc, off, 64);
    if ((tid & 63) == 0) sm[tid >> 6] = acc;
    __syncthreads();
    if (tid == 0)
        partial[j] = sm[0] + sm[1] + sm[2] + sm[3];
}

// ---------------------------------------------------------------------------
// Stage 3: combine partials + bias + relu, dot with W2, relu, sigmoid.
// ---------------------------------------------------------------------------
__global__ __launch_bounds__(128) void k_final_v2(
    const float* __restrict__ partial, // [256]
    const float* __restrict__ b1,      // [H1]
    const float* __restrict__ W2,      // [1, H1]
    const float* __restrict__ b2,      // [1]
    float* __restrict__ out)           // [1]
{
    __shared__ float sm[2];
    const int tid = threadIdx.x;
    float v = fmaxf(partial[2 * tid] + partial[2 * tid + 1] + b1[tid], 0.f)
              * W2[tid];
    #pragma unroll
    for (int off = 32; off > 0; off >>= 1)
        v += __shfl_xor(v, off, 64);
    if ((tid & 63) == 0) sm[tid >> 6] = v;
    __syncthreads();
    if (tid == 0) {
        float z = sm[0] + sm[1] + b2[0];
        z = fmaxf(z, 0.f);
        out[0] = 1.f / (1.f + expf(-z));
    }
}

extern "C" void kernel_launch(void* const* d_in, const int* in_sizes, int n_in,
                              void* d_out, int out_size, void* d_ws, size_t ws_size,
                              hipStream_t stream) {
    const float* x     = (const float*)d_in[0];
    const float* Wfc   = (const float*)d_in[1];
    const float* bfc   = (const float*)d_in[2];
    const float* Kc    = (const float*)d_in[3];
    const float* bconv = (const float*)d_in[4];
    const float* W1    = (const float*)d_in[5];
    const float* b1    = (const float*)d_in[6];
    const float* W2    = (const float*)d_in[7];
    const float* b2    = (const float*)d_in[8];
    float* out = (float*)d_out;

    float* concat  = (float*)d_ws;         // [CATN]
    float* partial = concat + CATN;        // [256]

    k_front_v9 <<<FCB2 + (CONVN / 256), 256, 0, stream>>>(
        x, Wfc, bfc, Kc, bconv, concat);
    k_layer1_v2<<<256, 256, 0, stream>>>(W1, concat, partial);
    k_final_v2 <<<1, 128, 0, stream>>>(partial, b1, W2, b2, out);
}